// Round 7
// baseline (1902.452 us; speedup 1.0000x reference)
//
#include <hip/hip_runtime.h>
#include <math.h>
#include <stdint.h>

#define HP 256
#define PTSTOT 8              // points per workgroup (two groups of 4)
#define PSTR 264              // halves per plane row (dw-stride 132 == 4 mod 32 -> 0-conflict, measured)
#define NLAYER 6
#define WT_ELEMS (6*256*256)  // per hi/lo array, fp16

typedef _Float16 half8 __attribute__((ext_vector_type(8)));
typedef float  float16v __attribute__((ext_vector_type(16)));

// f32 extras section (float offsets within section)
#define C_WI 0                // [3][256]
#define C_BI 768              // [256]
#define C_BH 1024             // [6][256]
#define C_WO 2560             // [256][4]
#define C_TOT 3584

__device__ __forceinline__ float fast_tanh(float x) {
    float e = __expf(2.0f * x);
    return 1.0f - __fdividef(2.0f, e + 1.0f);
}

__device__ __forceinline__ float16v zero16() {
    float16v z;
    #pragma unroll
    for (int i = 0; i < 16; ++i) z[i] = 0.0f;
    return z;
}

#define MFMA16(A,B,Cc) __builtin_amdgcn_mfma_f32_32x32x16_f16((A),(B),(Cc),0,0,0)

// ---------------- prep: transpose + split weights ----------------
__global__ void prep_kernel(const float* __restrict__ W_in, const float* __restrict__ b_in,
                            const float* __restrict__ W_h,  const float* __restrict__ b_h,
                            const float* __restrict__ W_out, void* __restrict__ wsv)
{
    _Float16* wt_hi = (_Float16*)wsv;
    _Float16* wt_lo = wt_hi + WT_ELEMS;
    float* cf = (float*)((char*)wsv + (size_t)2 * WT_ELEMS * 2);

    int i0 = blockIdx.x * blockDim.x + threadIdx.x;
    int stride = gridDim.x * blockDim.x;
    for (int i = i0; i < WT_ELEMS; i += stride) {
        int l = i >> 16, n = (i >> 8) & 255, k = i & 255;
        float w = (n < 250 && k < 250) ? W_h[(l*250 + k)*250 + n] : 0.0f;  // Wt[l][n][k]
        _Float16 h = (_Float16)w;
        _Float16 lo = (_Float16)((w - (float)h) * 1024.0f);
        wt_hi[i] = h; wt_lo[i] = lo;
    }
    for (int i = i0; i < C_TOT; i += stride) {
        float v = 0.0f;
        if (i < C_BI) { int r = i >> 8, j = i & 255; if (j < 250) v = W_in[r*250 + j]; }
        else if (i < C_BH) { int j = i - C_BI; if (j < 250) v = b_in[j]; }
        else if (i < C_WO) { int idx = i - C_BH; int l = idx >> 8, j = idx & 255; if (j < 250) v = b_h[l*250 + j]; }
        else { int idx = i - C_WO; int k = idx >> 2, o = idx & 3; if (k < 250) v = W_out[k*4 + o]; }
        cf[i] = v;
    }
}

// PHASE: K-loop for group GK layer LK (fills KM*/KC*) interleaved with epilogue
// for group GE layer LE (consumes EM*/EC*, writes A planes of GE in place).
// DOK/DOE are compile-time 0/1 literals. Groups always differ when both on.
#define PHASE(DOK, GK, LK, KM0,KM1,KC0,KC1, DOE, GE, LE, EM0,EM1,EC0,EC1) do { \
  const _Float16* ph0_ = wt_hi; const _Float16* pl0_ = wt_lo;                  \
  const _Float16* ph1_ = wt_hi; const _Float16* pl1_ = wt_lo;                  \
  half8 b0h_{}, b0l_{}, b1h_{}, b1l_{}, n0h_{}, n0l_{}, n1h_{}, n1l_{};       \
  half8 a0h_{}, a0l_{}, p0h_{}, p0l_{}, p1h_{}, p1l_{}, na0h_{}, na0l_{};     \
  int abase_ = 0;                                                              \
  if (DOK) {                                                                   \
    ph0_ = wt_hi + (((size_t)(LK)) << 16) + (size_t)n0 * 256 + 8*hi5;          \
    pl0_ = wt_lo + (((size_t)(LK)) << 16) + (size_t)n0 * 256 + 8*hi5;          \
    ph1_ = ph0_ + 32*256;  pl1_ = pl0_ + 32*256;                               \
    b0h_ = *(const half8*)(ph0_);     b0l_ = *(const half8*)(pl0_);            \
    b1h_ = *(const half8*)(ph1_);     b1l_ = *(const half8*)(pl1_);            \
    n0h_ = *(const half8*)(ph0_+16);  n0l_ = *(const half8*)(pl0_+16);         \
    n1h_ = *(const half8*)(ph1_+16);  n1l_ = *(const half8*)(pl1_+16);         \
    KM0 = zero16(); KM1 = zero16(); KC0 = zero16(); KC1 = zero16();            \
    abase_ = (32*(GK) + lo5) * PSTR + 8*hi5;                                   \
    a0h_ = *(const half8*)&Ah[abase_];  a0l_ = *(const half8*)&Al[abase_];     \
  }                                                                            \
  float ebb0_ = 0.f, ebb1_ = 0.f, ecc_ = 0.f;                                  \
  if (DOE) {                                                                   \
    ebb0_ = cf[C_BH + ((LE) << 8) + n0];                                       \
    ebb1_ = cf[C_BH + ((LE) << 8) + n0 + 32];                                  \
    ecc_  = 10.0f * act[(LE) + 1];                                             \
  }                                                                            \
  _Pragma("unroll")                                                            \
  for (int i_ = 0; i_ < 8; ++i_) {                                             \
    if (DOK) {                                                                 \
      _Pragma("unroll")                                                        \
      for (int u_ = 0; u_ < 2; ++u_) {                                         \
        const int s_ = 2*i_ + u_;                                              \
        const int so2_ = 16 * ((s_ + 2) & 15);                                 \
        p0h_ = *(const half8*)(ph0_ + so2_);  p0l_ = *(const half8*)(pl0_ + so2_); \
        p1h_ = *(const half8*)(ph1_ + so2_);  p1l_ = *(const half8*)(pl1_ + so2_); \
        const int sa_ = 16 * ((s_ + 1) & 15);                                  \
        na0h_ = *(const half8*)&Ah[abase_ + sa_];                              \
        na0l_ = *(const half8*)&Al[abase_ + sa_];                              \
        KM0 = MFMA16(a0h_, b0h_, KM0);  KC0 = MFMA16(a0h_, b0l_, KC0);         \
        KM1 = MFMA16(a0h_, b1h_, KM1);  KC1 = MFMA16(a0h_, b1l_, KC1);         \
        KC0 = MFMA16(a0l_, b0h_, KC0);  KC1 = MFMA16(a0l_, b1h_, KC1);         \
        a0h_ = na0h_;  a0l_ = na0l_;                                           \
        b0h_ = n0h_; b0l_ = n0l_; b1h_ = n1h_; b1l_ = n1l_;                    \
        n0h_ = p0h_; n0l_ = p0l_; n1h_ = p1h_; n1l_ = p1l_;                    \
      }                                                                        \
    }                                                                          \
    if (DOE) {                                                                 \
      const int t_ = i_ >> 2, p_ = i_ & 3;                                     \
      float za_ = (t_ ? (EM1)[4*p_+0] : (EM0)[4*p_+0])                         \
                + (t_ ? (EC1)[4*p_+0] : (EC0)[4*p_+0]) * (1.0f/1024.0f);       \
      float zb_ = (t_ ? (EM1)[4*p_+1] : (EM0)[4*p_+1])                         \
                + (t_ ? (EC1)[4*p_+1] : (EC0)[4*p_+1]) * (1.0f/1024.0f);       \
      float zg_ = (t_ ? (EM1)[4*p_+2] : (EM0)[4*p_+2])                         \
                + (t_ ? (EC1)[4*p_+2] : (EC0)[4*p_+2]) * (1.0f/1024.0f);       \
      float zd_ = (t_ ? (EM1)[4*p_+3] : (EM0)[4*p_+3])                         \
                + (t_ ? (EC1)[4*p_+3] : (EC0)[4*p_+3]) * (1.0f/1024.0f);       \
      if (!hi5) za_ += (t_ ? ebb1_ : ebb0_);                                   \
      float e0_ = __shfl_xor(za_, 32);                                         \
      float e1_ = __shfl_xor(zb_, 32);                                         \
      float e2_ = __shfl_xor(zg_, 32);                                         \
      float zv_ = hi5 ? e0_ : za_;                                             \
      float y_  = fast_tanh(ecc_ * zv_);                                       \
      float sh_ = 1.0f - y_*y_;                                                \
      float cs_ = ecc_ * sh_;                                                  \
      float o0_, o1_, o2_, o3_;                                                \
      if (!hi5) { o0_ = y_; o1_ = cs_*zb_; o2_ = cs_*zg_; o3_ = cs_*zd_; }     \
      else {                                                                   \
        float m2_ = -2.0f * ecc_ * cs_ * y_;                                   \
        o0_ = cs_*za_ + m2_*e1_*e1_;                                           \
        o1_ = cs_*zb_ + m2_*e2_*e2_;                                           \
        o2_ = cs_*zg_ + m2_*e1_*e2_;                                           \
        o3_ = 0.0f;                                                            \
      }                                                                        \
      const int ncol_ = 64*qtr + 32*t_ + lo5;                                  \
      const int rb_ = (32*(GE) + 8*p_ + 4*hi5) * PSTR + ncol_;                 \
      _Float16 h0_ = (_Float16)o0_;                                            \
      Ah[rb_         ] = h0_;  Al[rb_         ] = (_Float16)((o0_-(float)h0_)*1024.0f); \
      _Float16 h1_ = (_Float16)o1_;                                            \
      Ah[rb_ +   PSTR] = h1_;  Al[rb_ +   PSTR] = (_Float16)((o1_-(float)h1_)*1024.0f); \
      _Float16 h2_ = (_Float16)o2_;                                            \
      Ah[rb_ + 2*PSTR] = h2_;  Al[rb_ + 2*PSTR] = (_Float16)((o2_-(float)h2_)*1024.0f); \
      _Float16 h3_ = (_Float16)o3_;                                            \
      Ah[rb_ + 3*PSTR] = h3_;  Al[rb_ + 3*PSTR] = (_Float16)((o3_-(float)h3_)*1024.0f); \
    }                                                                          \
  }                                                                            \
} while (0)

// ---------------- fused PINN kernel ----------------
// 256 threads = 4 waves; wave qtr owns cols 64*qtr..+63 (subtiles t=0,1).
// Rows: 64 = 2 groups x (4 points x 8 channels). Two-group software pipeline:
// each phase runs one group's K-loop interleaved with the other's epilogue.
__launch_bounds__(256, 2)
__global__ void pinn_mfma(const float* __restrict__ xg, const float* __restrict__ yg,
                          const float* __restrict__ tg, const void* __restrict__ wsv,
                          const float* __restrict__ b_out, const float* __restrict__ act,
                          float* __restrict__ out, int N)
{
    __shared__ _Float16 Ah[64 * PSTR];
    __shared__ _Float16 Al[64 * PSTR];
    __shared__ float zo[PTSTOT][28];

    const _Float16* __restrict__ wt_hi = (const _Float16*)wsv;
    const _Float16* __restrict__ wt_lo = wt_hi + WT_ELEMS;
    const float* __restrict__ cf = (const float*)((const char*)wsv + (size_t)2 * WT_ELEMS * 2);

    const int tid  = threadIdx.x;
    const int lane = tid & 63;
    const int qtr  = tid >> 6;
    const int lo5  = lane & 31;
    const int hi5  = lane >> 5;
    const int n0   = 64*qtr + lo5;

    // ---------- input layer jet: thread j = tid handles neuron j for all 8 points ----------
    {
        int j = tid;
        float wi0 = cf[C_WI + j], wi1 = cf[C_WI + 256 + j], wi2 = cf[C_WI + 512 + j];
        float biv = cf[C_BI + j];
        float c0 = 10.0f * act[0];
        #pragma unroll
        for (int p = 0; p < PTSTOT; ++p) {
            int gp = blockIdx.x * PTSTOT + p;
            gp = gp < N ? gp : N - 1;
            float px = xg[gp], py = yg[gp], pt = tg[gp];
            float z = px*wi0 + py*wi1 + pt*wi2 + biv;
            float y = fast_tanh(c0 * z);
            float s = 1.0f - y*y;
            float cs = c0 * s;
            float m2 = -2.0f * c0 * cs * y;
            float o[8];
            o[0] = y;           o[1] = cs*wi0;      o[2] = cs*wi1;      o[3] = cs*wi2;
            o[4] = m2*wi0*wi0;  o[5] = m2*wi1*wi1;  o[6] = m2*wi0*wi1;  o[7] = 0.0f;
            #pragma unroll
            for (int c = 0; c < 8; ++c) {
                _Float16 h = (_Float16)o[c];
                Ah[(8*p + c)*PSTR + j] = h;
                Al[(8*p + c)*PSTR + j] = (_Float16)((o[c] - (float)h) * 1024.0f);
            }
        }
    }

    float16v Am0, Am1, Ac0, Ac1;   // group 0 accumulators
    float16v Bm0, Bm1, Bc0, Bc1;   // group 1 accumulators

    __syncthreads();
    // P0: K(g0, L0) only
    PHASE(1, 0, 0, Am0,Am1,Ac0,Ac1,  0, 0, 0, Am0,Am1,Ac0,Ac1);

    for (int L = 0; L < NLAYER; ++L) {
        __syncthreads();
        // K(g1, L) + E(g0, L)
        PHASE(1, 1, L, Bm0,Bm1,Bc0,Bc1,  1, 0, L, Am0,Am1,Ac0,Ac1);
        __syncthreads();
        if (L + 1 < NLAYER) {
            // K(g0, L+1) + E(g1, L)
            PHASE(1, 0, L+1, Am0,Am1,Ac0,Ac1,  1, 1, L, Bm0,Bm1,Bc0,Bc1);
        } else {
            // tail: E(g1, L) only
            PHASE(0, 0, 0, Am0,Am1,Ac0,Ac1,  1, 1, L, Bm0,Bm1,Bc0,Bc1);
        }
    }

    // ---------- output layer: 28 dots per point ----------
    __syncthreads();
    if (tid < PTSTOT * 28) {
        int p = tid / 28, idx = tid % 28;
        int c = idx >> 2, o = idx & 3;
        const _Float16* rh = &Ah[(8*p + c) * PSTR];
        const _Float16* rl = &Al[(8*p + c) * PSTR];
        float s = 0.0f;
        for (int k = 0; k < HP; ++k)
            s += ((float)rh[k] + (float)rl[k] * (1.0f/1024.0f)) * cf[C_WO + 4*k + o];
        zo[p][idx] = s;
    }
    __syncthreads();

    // ---------- heads + PDE residuals ----------
    if (tid < PTSTOT) {
        int gp = blockIdx.x * PTSTOT + tid;
        if (gp < N) {
            float zc[7][4];
            #pragma unroll
            for (int c = 0; c < 7; ++c)
                #pragma unroll
                for (int o = 0; o < 4; ++o)
                    zc[c][o] = zo[tid][c*4 + o] + (c == 0 ? b_out[o] : 0.0f);

            float u  = zc[0][0], vv = zc[0][1];
            float u_x = zc[1][0], u_y = zc[2][0], u_t = zc[3][0];
            float u_xx = zc[4][0], u_yy = zc[5][0];
            float v_x = zc[1][1], v_y = zc[2][1], v_t = zc[3][1];
            float v_xx = zc[4][1], v_yy = zc[5][1];

            float ep  = expf(zc[0][2]);
            float p_x = ep * zc[1][2], p_y = ep * zc[2][2];

            float a   = 1.0f / (1.0f + expf(-zc[0][3]));
            float sp  = a * (1.0f - a);
            float spp = sp * (1.0f - 2.0f*a);
            float z1a = zc[1][3], z2a = zc[2][3];
            float a_x = sp * z1a, a_y = sp * z2a, a_t = sp * zc[3][3];
            float a_xx = spp*z1a*z1a + sp*zc[4][3];
            float a_yy = spp*z2a*z2a + sp*zc[5][3];
            float a_xy = spp*z1a*z2a + sp*zc[6][3];

            float mu_x = -9.0f*a_x, mu_y = -9.0f*a_y;
            float mu   = 10.0f - 9.0f*a;
            float rr   = 1.0f - 0.9f*a;
            float g  = sqrtf(a_x*a_x + a_y*a_y + 2.220446049250313e-16f);
            float g3 = g*g*g;
            float curv = -((a_xx + a_yy)/g
                         - (a_x*a_x*a_xx + a_y*a_y*a_yy + 2.0f*a_x*a_y*a_xy)/g3);
            float one_Re   = mu   * 0.002f;
            float one_Re_x = mu_x * 0.002f;
            float one_Re_y = mu_y * 0.002f;

            float PDE_m = u_x + v_y;
            float PDE_a = a_t + u*a_x + vv*a_y;
            float PDE_u = (u_t + u*u_x + vv*u_y)*rr + p_x - 0.049f*curv*a_x
                        - one_Re*(u_xx + u_yy) - 2.0f*one_Re_x*u_x - one_Re_y*(u_y + v_x);
            float PDE_v = (v_t + u*v_x + vv*v_y)*rr + p_y - 0.049f*curv*a_y
                        - one_Re*(v_xx + v_yy) - rr*0.49f
                        - 2.0f*one_Re_y*v_y - one_Re_x*(u_y + v_x);

            out[0*N + gp] = PDE_m;
            out[1*N + gp] = PDE_u;
            out[2*N + gp] = PDE_v;
            out[3*N + gp] = PDE_a;
        }
    }
}

extern "C" void kernel_launch(void* const* d_in, const int* in_sizes, int n_in,
                              void* d_out, int out_size, void* d_ws, size_t ws_size,
                              hipStream_t stream)
{
    const float* x     = (const float*)d_in[0];
    const float* y     = (const float*)d_in[1];
    const float* t     = (const float*)d_in[2];
    const float* W_in  = (const float*)d_in[3];
    const float* b_in  = (const float*)d_in[4];
    const float* W_h   = (const float*)d_in[5];
    const float* b_h   = (const float*)d_in[6];
    const float* W_out = (const float*)d_in[7];
    const float* b_out = (const float*)d_in[8];
    const float* act   = (const float*)d_in[9];
    float* out = (float*)d_out;
    int N = in_sizes[0];

    hipLaunchKernelGGL(prep_kernel, dim3(512), dim3(256), 0, stream,
                       W_in, b_in, W_h, b_h, W_out, d_ws);
    int nb = (N + PTSTOT - 1) / PTSTOT;
    hipLaunchKernelGGL(pinn_mfma, dim3(nb), dim3(256), 0, stream,
                       x, y, t, d_ws, b_out, act, out, N);
}

// Round 9
// 469.734 us; speedup vs baseline: 4.0501x; 4.0501x over previous
//
#include <hip/hip_runtime.h>
#include <math.h>
#include <stdint.h>

#define HP 256
#define PTS 8                 // points per workgroup
#define ROWS 64               // 8 points x 8 channels (ch7 dummy)
#define PSTR 264              // halves per A row (dw-stride 132 == 4 mod 32 -> 0-conflict, measured)
#define NLAYER 6
#define WT_ELEMS (6*256*256)  // fp16 transposed weights

typedef _Float16 half8 __attribute__((ext_vector_type(8)));
typedef float  float16v __attribute__((ext_vector_type(16)));

// f32 extras section (float offsets within section; section starts at byte WT_ELEMS*2)
#define C_WI 0                // [3][256]
#define C_BI 768              // [256]
#define C_BH 1024             // [6][256]
#define C_WO 2560             // [256][4]
#define C_TOT 3584

__device__ __forceinline__ float fast_tanh(float x) {
    float e = __expf(2.0f * x);
    return 1.0f - __fdividef(2.0f, e + 1.0f);
}

__device__ __forceinline__ float16v zero16() {
    float16v z;
    #pragma unroll
    for (int i = 0; i < 16; ++i) z[i] = 0.0f;
    return z;
}

#define MFMA16(A,B,Cc) __builtin_amdgcn_mfma_f32_32x32x16_f16((A),(B),(Cc),0,0,0)

// ---------------- prep: transpose weights to fp16 ----------------
__global__ void prep_kernel(const float* __restrict__ W_in, const float* __restrict__ b_in,
                            const float* __restrict__ W_h,  const float* __restrict__ b_h,
                            const float* __restrict__ W_out, void* __restrict__ wsv)
{
    _Float16* wt = (_Float16*)wsv;
    float* cf = (float*)((char*)wsv + (size_t)WT_ELEMS * 2);

    int i0 = blockIdx.x * blockDim.x + threadIdx.x;
    int stride = gridDim.x * blockDim.x;
    for (int i = i0; i < WT_ELEMS; i += stride) {
        int l = i >> 16, n = (i >> 8) & 255, k = i & 255;
        float w = (n < 250 && k < 250) ? W_h[(l*250 + k)*250 + n] : 0.0f;  // Wt[l][n][k]
        wt[i] = (_Float16)w;
    }
    for (int i = i0; i < C_TOT; i += stride) {
        float v = 0.0f;
        if (i < C_BI) { int r = i >> 8, j = i & 255; if (j < 250) v = W_in[r*250 + j]; }
        else if (i < C_BH) { int j = i - C_BI; if (j < 250) v = b_in[j]; }
        else if (i < C_WO) { int idx = i - C_BH; int l = idx >> 8, j = idx & 255; if (j < 250) v = b_h[l*250 + j]; }
        else { int idx = i - C_WO; int k = idx >> 2, o = idx & 3; if (k < 250) v = W_out[k*4 + o]; }
        cf[i] = v;
    }
}

// ---------------- fused PINN kernel ----------------
// 256 threads = 4 waves. Wave qtr owns cols 64*qtr..+63 (two 32-col subtiles t=0,1),
// all 64 rows (two 32-row tiles). MFMA 32x32x16 f16, SINGLE-PASS fp16 (no hi/lo comp).
// A in one fp16 LDS plane; A(s+1) + B(s+2) register prefetch, no wrap-waste loads.
__launch_bounds__(256, 3)
__global__ void pinn_mfma(const float* __restrict__ xg, const float* __restrict__ yg,
                          const float* __restrict__ tg, const void* __restrict__ wsv,
                          const float* __restrict__ b_out, const float* __restrict__ act,
                          float* __restrict__ out, int N)
{
    __shared__ _Float16 Ah[ROWS * PSTR];
    __shared__ float zo[PTS][28];

    const _Float16* __restrict__ wt = (const _Float16*)wsv;
    const float* __restrict__ cf = (const float*)((const char*)wsv + (size_t)WT_ELEMS * 2);

    const int tid  = threadIdx.x;
    const int lane = tid & 63;
    const int qtr  = tid >> 6;        // col quarter: 64*qtr
    const int lo5  = lane & 31;
    const int hi5  = lane >> 5;
    const int n0   = 64*qtr + lo5;

    // ---------- input layer jet: thread j = tid handles neuron j for all 8 points ----------
    {
        int j = tid;
        float wi0 = cf[C_WI + j], wi1 = cf[C_WI + 256 + j], wi2 = cf[C_WI + 512 + j];
        float biv = cf[C_BI + j];
        float c0 = 10.0f * act[0];
        #pragma unroll
        for (int p = 0; p < PTS; ++p) {
            int gp = blockIdx.x * PTS + p;
            gp = gp < N ? gp : N - 1;
            float px = xg[gp], py = yg[gp], pt = tg[gp];
            float z = px*wi0 + py*wi1 + pt*wi2 + biv;
            float y = fast_tanh(c0 * z);
            float s = 1.0f - y*y;
            float cs = c0 * s;
            float m2 = -2.0f * c0 * cs * y;
            Ah[(8*p + 0)*PSTR + j] = (_Float16)y;
            Ah[(8*p + 1)*PSTR + j] = (_Float16)(cs*wi0);
            Ah[(8*p + 2)*PSTR + j] = (_Float16)(cs*wi1);
            Ah[(8*p + 3)*PSTR + j] = (_Float16)(cs*wi2);
            Ah[(8*p + 4)*PSTR + j] = (_Float16)(m2*wi0*wi0);
            Ah[(8*p + 5)*PSTR + j] = (_Float16)(m2*wi1*wi1);
            Ah[(8*p + 6)*PSTR + j] = (_Float16)(m2*wi0*wi1);
            Ah[(8*p + 7)*PSTR + j] = (_Float16)0.0f;
        }
    }

    // ---------- hidden layers ----------
    for (int L = 0; L < NLAYER; ++L) {
        float cc = 10.0f * act[L + 1];
        const _Float16* __restrict__ wbh = wt + ((size_t)L << 16);

        const _Float16* ph0 = wbh + (size_t)n0 * 256 + 8*hi5;   // t=0 neuron row
        const _Float16* ph1 = ph0 + 32 * 256;                   // t=1: n0+32

        // B prefetch (global, read-only) issued BEFORE the barrier
        half8 b0 = *(const half8*)(ph0);
        half8 b1 = *(const half8*)(ph1);
        half8 nb0 = *(const half8*)(ph0 + 16);
        half8 nb1 = *(const half8*)(ph1 + 16);

        float16v m00 = zero16(), m01 = zero16(), m10 = zero16(), m11 = zero16();

        __syncthreads();                              // A plane stable

        const int abase = lo5 * PSTR + 8*hi5;
        half8 a0 = *(const half8*)&Ah[abase];
        half8 a1 = *(const half8*)&Ah[abase + 32*PSTR];

        #pragma unroll
        for (int s = 0; s < 16; ++s) {
            half8 p0{}, p1{}, na0{}, na1{};
            if (s < 14) {                             // B prefetch distance 2, no wrap waste
                p0 = *(const half8*)(ph0 + 16*(s + 2));
                p1 = *(const half8*)(ph1 + 16*(s + 2));
            }
            if (s < 15) {                             // A prefetch distance 1
                na0 = *(const half8*)&Ah[abase + 16*(s + 1)];
                na1 = *(const half8*)&Ah[abase + 32*PSTR + 16*(s + 1)];
            }
            m00 = MFMA16(a0, b0, m00);
            m01 = MFMA16(a1, b0, m01);
            m10 = MFMA16(a0, b1, m10);
            m11 = MFMA16(a1, b1, m11);
            a0 = na0; a1 = na1;
            b0 = nb0; b1 = nb1;
            nb0 = p0; nb1 = p1;
        }

        __syncthreads();                              // all reads done before overwrite

        float bb0 = cf[C_BH + (L << 8) + n0];         // hidden bias
        float bb1 = cf[C_BH + (L << 8) + n0 + 32];

        #pragma unroll
        for (int t = 0; t < 2; ++t) {
            float bb = t ? bb1 : bb0;
            int ncol = 64*qtr + 32*t + lo5;
            #pragma unroll
            for (int rt = 0; rt < 2; ++rt) {
                float16v mv = t ? (rt ? m11 : m10) : (rt ? m01 : m00);
                #pragma unroll
                for (int p = 0; p < 4; ++p) {
                    float za  = mv[4*p+0];
                    float zb  = mv[4*p+1];
                    float zc_ = mv[4*p+2];
                    float zd  = mv[4*p+3];
                    if (!hi5) za += bb;               // bias on value channel
                    float e0 = __shfl_xor(za, 32);
                    float e1 = __shfl_xor(zb, 32);
                    float e2 = __shfl_xor(zc_, 32);
                    float zval = hi5 ? e0 : za;
                    float y  = fast_tanh(cc * zval);
                    float sh = 1.0f - y*y;
                    float cs = cc * sh;
                    float o0, o1, o2, o3;
                    if (!hi5) {
                        o0 = y; o1 = cs*zb; o2 = cs*zc_; o3 = cs*zd;
                    } else {
                        float m2c = -2.0f * cc * cs * y;
                        float zx = e1, zy = e2;
                        o0 = cs*za  + m2c*zx*zx;      // ch4
                        o1 = cs*zb  + m2c*zy*zy;      // ch5
                        o2 = cs*zc_ + m2c*zx*zy;      // ch6
                        o3 = 0.0f;                    // ch7 dummy (hi5 half)
                    }
                    int rbase = (32*rt + 8*p + 4*hi5) * PSTR + ncol;
                    Ah[rbase + 0*PSTR] = (_Float16)o0;
                    Ah[rbase + 1*PSTR] = (_Float16)o1;
                    Ah[rbase + 2*PSTR] = (_Float16)o2;
                    Ah[rbase + 3*PSTR] = (_Float16)o3;
                }
            }
        }
    }

    // ---------- output layer: 28 dots per point ----------
    __syncthreads();
    if (tid < PTS * 28) {
        int p = tid / 28, idx = tid % 28;
        int c = idx >> 2, o = idx & 3;
        const _Float16* rh = &Ah[(8*p + c) * PSTR];
        float s = 0.0f;
        for (int k = 0; k < HP; ++k)
            s += (float)rh[k] * cf[C_WO + 4*k + o];
        zo[p][idx] = s;
    }
    __syncthreads();

    // ---------- heads + PDE residuals ----------
    if (tid < PTS) {
        int gp = blockIdx.x * PTS + tid;
        if (gp < N) {
            float zc[7][4];
            #pragma unroll
            for (int c = 0; c < 7; ++c)
                #pragma unroll
                for (int o = 0; o < 4; ++o)
                    zc[c][o] = zo[tid][c*4 + o] + (c == 0 ? b_out[o] : 0.0f);

            float u  = zc[0][0], vv = zc[0][1];
            float u_x = zc[1][0], u_y = zc[2][0], u_t = zc[3][0];
            float u_xx = zc[4][0], u_yy = zc[5][0];
            float v_x = zc[1][1], v_y = zc[2][1], v_t = zc[3][1];
            float v_xx = zc[4][1], v_yy = zc[5][1];

            float ep  = expf(zc[0][2]);
            float p_x = ep * zc[1][2], p_y = ep * zc[2][2];

            float a   = 1.0f / (1.0f + expf(-zc[0][3]));
            float sp  = a * (1.0f - a);
            float spp = sp * (1.0f - 2.0f*a);
            float z1a = zc[1][3], z2a = zc[2][3];
            float a_x = sp * z1a, a_y = sp * z2a, a_t = sp * zc[3][3];
            float a_xx = spp*z1a*z1a + sp*zc[4][3];
            float a_yy = spp*z2a*z2a + sp*zc[5][3];
            float a_xy = spp*z1a*z2a + sp*zc[6][3];

            float mu_x = -9.0f*a_x, mu_y = -9.0f*a_y;
            float mu   = 10.0f - 9.0f*a;
            float rr   = 1.0f - 0.9f*a;
            float g  = sqrtf(a_x*a_x + a_y*a_y + 2.220446049250313e-16f);
            float g3 = g*g*g;
            float curv = -((a_xx + a_yy)/g
                         - (a_x*a_x*a_xx + a_y*a_y*a_yy + 2.0f*a_x*a_y*a_xy)/g3);
            float one_Re   = mu   * 0.002f;
            float one_Re_x = mu_x * 0.002f;
            float one_Re_y = mu_y * 0.002f;

            float PDE_m = u_x + v_y;
            float PDE_a = a_t + u*a_x + vv*a_y;
            float PDE_u = (u_t + u*u_x + vv*u_y)*rr + p_x - 0.049f*curv*a_x
                        - one_Re*(u_xx + u_yy) - 2.0f*one_Re_x*u_x - one_Re_y*(u_y + v_x);
            float PDE_v = (v_t + u*v_x + vv*v_y)*rr + p_y - 0.049f*curv*a_y
                        - one_Re*(v_xx + v_yy) - rr*0.49f
                        - 2.0f*one_Re_y*v_y - one_Re_x*(u_y + v_x);

            out[0*N + gp] = PDE_m;
            out[1*N + gp] = PDE_u;
            out[2*N + gp] = PDE_v;
            out[3*N + gp] = PDE_a;
        }
    }
}

extern "C" void kernel_launch(void* const* d_in, const int* in_sizes, int n_in,
                              void* d_out, int out_size, void* d_ws, size_t ws_size,
                              hipStream_t stream)
{
    const float* x     = (const float*)d_in[0];
    const float* y     = (const float*)d_in[1];
    const float* t     = (const float*)d_in[2];
    const float* W_in  = (const float*)d_in[3];
    const float* b_in  = (const float*)d_in[4];
    const float* W_h   = (const float*)d_in[5];
    const float* b_h   = (const float*)d_in[6];
    const float* W_out = (const float*)d_in[7];
    const float* b_out = (const float*)d_in[8];
    const float* act   = (const float*)d_in[9];
    float* out = (float*)d_out;
    int N = in_sizes[0];

    hipLaunchKernelGGL(prep_kernel, dim3(512), dim3(256), 0, stream,
                       W_in, b_in, W_h, b_h, W_out, d_ws);
    int nb = (N + PTS - 1) / PTS;
    hipLaunchKernelGGL(pinn_mfma, dim3(nb), dim3(256), 0, stream,
                       x, y, t, d_ws, b_out, act, out, N);
}

// Round 10
// 455.093 us; speedup vs baseline: 4.1804x; 1.0322x over previous
//
#include <hip/hip_runtime.h>
#include <math.h>
#include <stdint.h>

#define HP 256
#define PTS 8                 // points per workgroup
#define ROWS 64               // 8 points x 8 channels (ch7 dummy)
#define PSTR 264              // halves per A row (dw-stride 132 == 4 mod 32 -> 0-conflict, measured)
#define NLAYER 6
#define WT_ELEMS (6*256*256)  // fp16 transposed weights

typedef _Float16 half8 __attribute__((ext_vector_type(8)));
typedef float  float16v __attribute__((ext_vector_type(16)));

// f32 extras section (float offsets within section; section starts at byte WT_ELEMS*2)
#define C_WI 0                // [3][256]
#define C_BI 768              // [256]
#define C_BH 1024             // [6][256]
#define C_WO 2560             // [256][4]
#define C_TOT 3584

__device__ __forceinline__ float fast_tanh(float x) {
    float e = __expf(2.0f * x);
    return 1.0f - __fdividef(2.0f, e + 1.0f);
}

__device__ __forceinline__ float16v zero16() {
    float16v z;
    #pragma unroll
    for (int i = 0; i < 16; ++i) z[i] = 0.0f;
    return z;
}

// A-row for (point P in 0..7, channel c in 0..7). Permuted so that in the
// 32x32 MFMA C-layout (row=(reg&3)+8*(reg>>2)+4*hi5) each lane's 4 reg-quads
// hold ch0-3 and ch4-7 of the SAME two points -> epilogue needs no shuffles.
__device__ __forceinline__ int arow(int P, int c) {
    return 32*(P >> 2) + 16*((P >> 1) & 1) + 4*(P & 1) + 8*(c >> 2) + (c & 3);
}

#define MFMA16(A,B,Cc) __builtin_amdgcn_mfma_f32_32x32x16_f16((A),(B),(Cc),0,0,0)

// ---------------- prep: transpose weights to fp16 ----------------
__global__ void prep_kernel(const float* __restrict__ W_in, const float* __restrict__ b_in,
                            const float* __restrict__ W_h,  const float* __restrict__ b_h,
                            const float* __restrict__ W_out, void* __restrict__ wsv)
{
    _Float16* wt = (_Float16*)wsv;
    float* cf = (float*)((char*)wsv + (size_t)WT_ELEMS * 2);

    int i0 = blockIdx.x * blockDim.x + threadIdx.x;
    int stride = gridDim.x * blockDim.x;
    for (int i = i0; i < WT_ELEMS; i += stride) {
        int l = i >> 16, n = (i >> 8) & 255, k = i & 255;
        float w = (n < 250 && k < 250) ? W_h[(l*250 + k)*250 + n] : 0.0f;  // Wt[l][n][k]
        wt[i] = (_Float16)w;
    }
    for (int i = i0; i < C_TOT; i += stride) {
        float v = 0.0f;
        if (i < C_BI) { int r = i >> 8, j = i & 255; if (j < 250) v = W_in[r*250 + j]; }
        else if (i < C_BH) { int j = i - C_BI; if (j < 250) v = b_in[j]; }
        else if (i < C_WO) { int idx = i - C_BH; int l = idx >> 8, j = idx & 255; if (j < 250) v = b_h[l*250 + j]; }
        else { int idx = i - C_WO; int k = idx >> 2, o = idx & 3; if (k < 250) v = W_out[k*4 + o]; }
        cf[i] = v;
    }
}

// ---------------- fused PINN kernel ----------------
// 256 threads = 4 waves. Wave qtr owns cols 64*qtr..+63 (two 32-col subtiles),
// all 64 rows (two 32-row tiles). MFMA 32x32x16 f16 single-pass.
// A rows permuted (arow) so epilogue is shuffle-free and divergence-free.
__launch_bounds__(256, 4)
__global__ void pinn_mfma(const float* __restrict__ xg, const float* __restrict__ yg,
                          const float* __restrict__ tg, const void* __restrict__ wsv,
                          const float* __restrict__ b_out, const float* __restrict__ act,
                          float* __restrict__ out, int N)
{
    __shared__ _Float16 Ah[ROWS * PSTR];
    __shared__ float zo[PTS][28];

    const _Float16* __restrict__ wt = (const _Float16*)wsv;
    const float* __restrict__ cf = (const float*)((const char*)wsv + (size_t)WT_ELEMS * 2);

    const int tid  = threadIdx.x;
    const int lane = tid & 63;
    const int qtr  = tid >> 6;        // col quarter: 64*qtr
    const int lo5  = lane & 31;
    const int hi5  = lane >> 5;
    const int n0   = 64*qtr + lo5;

    // ---------- input layer jet: thread j = tid handles neuron j for all 8 points ----------
    {
        int j = tid;
        float wi0 = cf[C_WI + j], wi1 = cf[C_WI + 256 + j], wi2 = cf[C_WI + 512 + j];
        float biv = cf[C_BI + j];
        float c0 = 10.0f * act[0];
        #pragma unroll
        for (int p = 0; p < PTS; ++p) {
            int gp = blockIdx.x * PTS + p;
            gp = gp < N ? gp : N - 1;
            float px = xg[gp], py = yg[gp], pt = tg[gp];
            float z = px*wi0 + py*wi1 + pt*wi2 + biv;
            float y = fast_tanh(c0 * z);
            float s = 1.0f - y*y;
            float cs = c0 * s;
            float m2 = -2.0f * c0 * cs * y;
            float o[8];
            o[0] = y;           o[1] = cs*wi0;      o[2] = cs*wi1;      o[3] = cs*wi2;
            o[4] = m2*wi0*wi0;  o[5] = m2*wi1*wi1;  o[6] = m2*wi0*wi1;  o[7] = 0.0f;
            #pragma unroll
            for (int c = 0; c < 8; ++c)
                Ah[arow(p, c)*PSTR + j] = (_Float16)o[c];
        }
    }

    // ---------- hidden layers ----------
    for (int L = 0; L < NLAYER; ++L) {
        float cc = 10.0f * act[L + 1];
        const _Float16* __restrict__ wbh = wt + ((size_t)L << 16);

        const _Float16* ph0 = wbh + (size_t)n0 * 256 + 8*hi5;   // t=0 neuron row
        const _Float16* ph1 = ph0 + 32 * 256;                   // t=1: n0+32

        // B prefetch (global, read-only) issued BEFORE the barrier
        half8 b0 = *(const half8*)(ph0);
        half8 b1 = *(const half8*)(ph1);
        half8 nb0 = *(const half8*)(ph0 + 16);
        half8 nb1 = *(const half8*)(ph1 + 16);

        float16v m00 = zero16(), m01 = zero16(), m10 = zero16(), m11 = zero16();

        __syncthreads();                              // A plane stable

        const int abase = lo5 * PSTR + 8*hi5;
        half8 a0 = *(const half8*)&Ah[abase];
        half8 a1 = *(const half8*)&Ah[abase + 32*PSTR];

        #pragma unroll
        for (int s = 0; s < 16; ++s) {
            half8 p0{}, p1{}, na0{}, na1{};
            if (s < 14) {                             // B prefetch distance 2, no wrap waste
                p0 = *(const half8*)(ph0 + 16*(s + 2));
                p1 = *(const half8*)(ph1 + 16*(s + 2));
            }
            if (s < 15) {                             // A prefetch distance 1
                na0 = *(const half8*)&Ah[abase + 16*(s + 1)];
                na1 = *(const half8*)&Ah[abase + 32*PSTR + 16*(s + 1)];
            }
            m00 = MFMA16(a0, b0, m00);
            m01 = MFMA16(a1, b0, m01);
            m10 = MFMA16(a0, b1, m10);
            m11 = MFMA16(a1, b1, m11);
            a0 = na0; a1 = na1;
            b0 = nb0; b1 = nb1;
            nb0 = p0; nb1 = p1;
        }

        __syncthreads();                              // all reads done before overwrite

        float bb0 = cf[C_BH + (L << 8) + n0];         // hidden bias (per output neuron)
        float bb1 = cf[C_BH + (L << 8) + n0 + 32];

        // ---- epilogue: shuffle-free, divergence-free, tanh once per point ----
        #pragma unroll
        for (int t = 0; t < 2; ++t) {
            float bb = t ? bb1 : bb0;
            int ncol = 64*qtr + 32*t + lo5;
            #pragma unroll
            for (int rt = 0; rt < 2; ++rt) {
                float16v mv = t ? (rt ? m11 : m10) : (rt ? m01 : m00);
                #pragma unroll
                for (int pp = 0; pp < 2; ++pp) {
                    // reg quad 2pp = ch0-3, quad 2pp+1 = ch4-7 of point (2pp+hi5) in tile rt
                    float z   = mv[8*pp+0] + bb;
                    float zx  = mv[8*pp+1];
                    float zy  = mv[8*pp+2];
                    float zt  = mv[8*pp+3];
                    float zxx = mv[8*pp+4];
                    float zyy = mv[8*pp+5];
                    float zxy = mv[8*pp+6];
                    float y   = fast_tanh(cc * z);
                    float sh  = 1.0f - y*y;
                    float cs  = cc * sh;
                    float m2c = -2.0f * cc * cs * y;
                    int r0 = (32*rt + 16*pp + 4*hi5) * PSTR + ncol;   // quad 2pp rows
                    Ah[r0 + 0*PSTR] = (_Float16)y;
                    Ah[r0 + 1*PSTR] = (_Float16)(cs*zx);
                    Ah[r0 + 2*PSTR] = (_Float16)(cs*zy);
                    Ah[r0 + 3*PSTR] = (_Float16)(cs*zt);
                    int r1 = r0 + 8*PSTR;                              // quad 2pp+1 rows
                    Ah[r1 + 0*PSTR] = (_Float16)(cs*zxx + m2c*zx*zx);
                    Ah[r1 + 1*PSTR] = (_Float16)(cs*zyy + m2c*zy*zy);
                    Ah[r1 + 2*PSTR] = (_Float16)(cs*zxy + m2c*zx*zy);
                    Ah[r1 + 3*PSTR] = (_Float16)0.0f;
                }
            }
        }
    }

    // ---------- output layer: 28 dots per point ----------
    __syncthreads();
    if (tid < PTS * 28) {
        int p = tid / 28, idx = tid % 28;
        int c = idx >> 2, o = idx & 3;
        const _Float16* rh = &Ah[arow(p, c) * PSTR];
        float s = 0.0f;
        for (int k = 0; k < HP; ++k)
            s += (float)rh[k] * cf[C_WO + 4*k + o];
        zo[p][idx] = s;
    }
    __syncthreads();

    // ---------- heads + PDE residuals ----------
    if (tid < PTS) {
        int gp = blockIdx.x * PTS + tid;
        if (gp < N) {
            float zc[7][4];
            #pragma unroll
            for (int c = 0; c < 7; ++c)
                #pragma unroll
                for (int o = 0; o < 4; ++o)
                    zc[c][o] = zo[tid][c*4 + o] + (c == 0 ? b_out[o] : 0.0f);

            float u  = zc[0][0], vv = zc[0][1];
            float u_x = zc[1][0], u_y = zc[2][0], u_t = zc[3][0];
            float u_xx = zc[4][0], u_yy = zc[5][0];
            float v_x = zc[1][1], v_y = zc[2][1], v_t = zc[3][1];
            float v_xx = zc[4][1], v_yy = zc[5][1];

            float ep  = expf(zc[0][2]);
            float p_x = ep * zc[1][2], p_y = ep * zc[2][2];

            float a   = 1.0f / (1.0f + expf(-zc[0][3]));
            float sp  = a * (1.0f - a);
            float spp = sp * (1.0f - 2.0f*a);
            float z1a = zc[1][3], z2a = zc[2][3];
            float a_x = sp * z1a, a_y = sp * z2a, a_t = sp * zc[3][3];
            float a_xx = spp*z1a*z1a + sp*zc[4][3];
            float a_yy = spp*z2a*z2a + sp*zc[5][3];
            float a_xy = spp*z1a*z2a + sp*zc[6][3];

            float mu_x = -9.0f*a_x, mu_y = -9.0f*a_y;
            float mu   = 10.0f - 9.0f*a;
            float rr   = 1.0f - 0.9f*a;
            float g  = sqrtf(a_x*a_x + a_y*a_y + 2.220446049250313e-16f);
            float g3 = g*g*g;
            float curv = -((a_xx + a_yy)/g
                         - (a_x*a_x*a_xx + a_y*a_y*a_yy + 2.0f*a_x*a_y*a_xy)/g3);
            float one_Re   = mu   * 0.002f;
            float one_Re_x = mu_x * 0.002f;
            float one_Re_y = mu_y * 0.002f;

            float PDE_m = u_x + v_y;
            float PDE_a = a_t + u*a_x + vv*a_y;
            float PDE_u = (u_t + u*u_x + vv*u_y)*rr + p_x - 0.049f*curv*a_x
                        - one_Re*(u_xx + u_yy) - 2.0f*one_Re_x*u_x - one_Re_y*(u_y + v_x);
            float PDE_v = (v_t + u*v_x + vv*v_y)*rr + p_y - 0.049f*curv*a_y
                        - one_Re*(v_xx + v_yy) - rr*0.49f
                        - 2.0f*one_Re_y*v_y - one_Re_x*(u_y + v_x);

            out[0*N + gp] = PDE_m;
            out[1*N + gp] = PDE_u;
            out[2*N + gp] = PDE_v;
            out[3*N + gp] = PDE_a;
        }
    }
}

extern "C" void kernel_launch(void* const* d_in, const int* in_sizes, int n_in,
                              void* d_out, int out_size, void* d_ws, size_t ws_size,
                              hipStream_t stream)
{
    const float* x     = (const float*)d_in[0];
    const float* y     = (const float*)d_in[1];
    const float* t     = (const float*)d_in[2];
    const float* W_in  = (const float*)d_in[3];
    const float* b_in  = (const float*)d_in[4];
    const float* W_h   = (const float*)d_in[5];
    const float* b_h   = (const float*)d_in[6];
    const float* W_out = (const float*)d_in[7];
    const float* b_out = (const float*)d_in[8];
    const float* act   = (const float*)d_in[9];
    float* out = (float*)d_out;
    int N = in_sizes[0];

    hipLaunchKernelGGL(prep_kernel, dim3(512), dim3(256), 0, stream,
                       W_in, b_in, W_h, b_h, W_out, d_ws);
    int nb = (N + PTS - 1) / PTS;
    hipLaunchKernelGGL(pinn_mfma, dim3(nb), dim3(256), 0, stream,
                       x, y, t, d_ws, b_out, act, out, N);
}